// Round 8
// baseline (248.349 us; speedup 1.0000x reference)
//
#include <hip/hip_runtime.h>
#include <math.h>

// ---- problem constants ----
#define NPIX 12544            // 64*14*14 pixels
#define CIN  2048
#define NB   64               // batch
#define PPIX 196              // pixels per batch image
#define PXB  7                // pixels per block (7 | 196: block never straddles images)
#define BPIMG 28              // blocks per image
#define NBLK (NB * BPIMG)     // 1792 blocks

typedef short  bf16x8 __attribute__((ext_vector_type(8)));
typedef float  f32x4  __attribute__((ext_vector_type(4)));

__device__ inline unsigned short f2bf(float f) {
    // round-to-nearest-even fp32 -> bf16
    unsigned int u = __float_as_uint(f);
    u = (u + 0x7fffu + ((u >> 16) & 1u)) >> 16;
    return (unsigned short)u;
}

// ---- kernel 0: W1 [2048][64] f32 -> Wf bf16 in MFMA-fragment order ----
// Wf flat index o = (((wv*8 + i)*4 + ct)*64 + lane)*8 + e  holds
// W1[k][n] with n = ct*16 + (lane&15), k = wv*256 + i*32 + (lane>>4)*8 + e.
// Phase-2 B-loads become ONE contiguous coalesced 1KB per (i,ct): no gather.
__global__ __launch_bounds__(256) void conv_w1(
    const float* __restrict__ W1, unsigned short* __restrict__ Wf)
{
    const int o    = blockIdx.x * 256 + threadIdx.x;   // 0..131071
    const int e    = o & 7;
    const int lane = (o >> 3) & 63;
    const int ct   = (o >> 9) & 3;
    const int i    = (o >> 11) & 7;
    const int wv   = (o >> 14) & 7;
    const int q = lane >> 4, l15 = lane & 15;
    const int n = ct * 16 + l15;
    const int k = wv * 256 + i * 32 + q * 8 + e;
    Wf[o] = f2bf(W1[k * 64 + n]);
}

// ---- kernel 1: FUSED attention scores + weighted GAP partials ----
// Block = 7 pixels of one image. 512 threads = 8 waves; wave wv owns the
// K-slice [wv*256, wv*256+256).
// Phase 1: x rows DMA'd global->LDS via global_load_lds (fire-and-forget,
//   cannot be compiler-sunk). LDS rows are linear; the global SOURCE address
//   is XOR-pre-swizzled per row (byte ^ (r<<4)) so the swizzled ds_read_b128
//   fragment reads are bank-conflict-free (rule: both-sides-or-neither).
// Phase 2: MFMA 16x16x32; A-rows 7..15 map to valid rows via l15 mod 7
//   (results unused). h1 K-partials reduced via LDS atomicAdd.
// Phase 3: MLP tail 64->16->8->1, 16 threads/pixel.
// Phase 4: a.x from the f32 LDS copy: thread t owns 4 channels, 7 scalar
//   FMAs, no shuffles. Per-block partial + a-sum to global.
__global__ __launch_bounds__(512) void fused_attn_gap(
    const float* __restrict__ x, const unsigned short* __restrict__ Wf,
    const float* __restrict__ b1,
    const float* __restrict__ W2, const float* __restrict__ b2,
    const float* __restrict__ W3, const float* __restrict__ b3,
    const float* __restrict__ W4, const float* __restrict__ b4,
    float* __restrict__ part2, float* __restrict__ asum_part)
{
    __shared__ float xs[PXB * CIN];      // 56 KB, rows XOR-swizzled (see above)
    __shared__ float h1s[16][68];        // bias-init, atomicAdd-accumulated
    __shared__ float h2s[16][16];
    __shared__ float h3s[16][8];
    __shared__ float a_s[16];

    const int t    = threadIdx.x;        // 0..511
    const int wv   = t >> 6;             // wave 0..7 -> K-slice & stage segment
    const int lane = t & 63;
    const int l15  = lane & 15;
    const int q    = lane >> 4;
    const int blk  = blockIdx.x;
    const size_t pix0 = (size_t)blk * PXB;

    // ---- phase 1: DMA stage. Wave wv stages segment wv (1KB) of each row. ----
#pragma unroll
    for (int r = 0; r < PXB; ++r) {
        const int swb = r << 4;                       // (r&7)<<4, r<7
        const float* gsrc = x + (pix0 + r) * (size_t)CIN + wv * 256
                          + (((lane * 16) ^ swb) >> 2);
        __builtin_amdgcn_global_load_lds(gsrc, &xs[r * CIN + wv * 256], 16, 0, 0);
    }
    if (t < 256)   // h1s[p][c] = b1[c]
        *(f32x4*)&h1s[t >> 4][(t & 15) * 4] = *(const f32x4*)(b1 + (t & 15) * 4);
    __syncthreads();   // drains vmcnt(0): DMA complete

    // ---- phase 2: MFMA over this wave's K-slice ----
    int rm = l15; if (rm >= 7) rm -= 7; if (rm >= 7) rm -= 7;   // valid row map
    const int sw = rm << 4;
    const char* xrow = (const char*)&xs[rm * CIN];

    f32x4 acc[4] = {{0,0,0,0},{0,0,0,0},{0,0,0,0},{0,0,0,0}};
    bf16x8 wA[4], wB[4];
#pragma unroll
    for (int ct = 0; ct < 4; ++ct)
        wA[ct] = *(const bf16x8*)(Wf + ((size_t)((wv * 8 + 0) * 4 + ct)) * 512 + lane * 8);
#pragma unroll
    for (int i = 0; i < 8; ++i) {
        if (i < 7) {   // prefetch next step's W (contiguous 1KB per (i,ct))
            if ((i & 1) == 0) {
#pragma unroll
                for (int ct = 0; ct < 4; ++ct)
                    wB[ct] = *(const bf16x8*)(Wf + ((size_t)((wv * 8 + i + 1) * 4 + ct)) * 512 + lane * 8);
            } else {
#pragma unroll
                for (int ct = 0; ct < 4; ++ct)
                    wA[ct] = *(const bf16x8*)(Wf + ((size_t)((wv * 8 + i + 1) * 4 + ct)) * 512 + lane * 8);
            }
        }
        // A-fragment: 8 f32 from swizzled LDS -> bf16
        const int b0 = wv * 1024 + i * 128 + q * 32;          // byte-in-row
        const f32x4 lo = *(const f32x4*)(xrow + ((b0)      ^ sw));
        const f32x4 hi = *(const f32x4*)(xrow + ((b0 + 16) ^ sw));
        bf16x8 af;
        af[0] = (short)f2bf(lo[0]); af[1] = (short)f2bf(lo[1]);
        af[2] = (short)f2bf(lo[2]); af[3] = (short)f2bf(lo[3]);
        af[4] = (short)f2bf(hi[0]); af[5] = (short)f2bf(hi[1]);
        af[6] = (short)f2bf(hi[2]); af[7] = (short)f2bf(hi[3]);
        if ((i & 1) == 0) {
#pragma unroll
            for (int ct = 0; ct < 4; ++ct)
                acc[ct] = __builtin_amdgcn_mfma_f32_16x16x32_bf16(af, wA[ct], acc[ct], 0, 0, 0);
        } else {
#pragma unroll
            for (int ct = 0; ct < 4; ++ct)
                acc[ct] = __builtin_amdgcn_mfma_f32_16x16x32_bf16(af, wB[ct], acc[ct], 0, 0, 0);
        }
    }
    // C/D: col = l15 (channel-in-tile), row = q*4 + r (pixel). K-split reduce.
#pragma unroll
    for (int ct = 0; ct < 4; ++ct)
#pragma unroll
        for (int r = 0; r < 4; ++r)
            atomicAdd(&h1s[q * 4 + r][ct * 16 + l15], acc[ct][r]);
    __syncthreads();

    // ---- phase 3: MLP tail (relu at h1 read) ----
    const int p = t >> 4;                // pixel (t<256)
    const int j = t & 15;
    if (t < 256) {
        float s = b2[j];
#pragma unroll
        for (int k = 0; k < 64; ++k)
            s = fmaf(fmaxf(h1s[p][k], 0.f), W2[k * 16 + j], s);
        h2s[p][j] = fmaxf(s, 0.f);
    }
    __syncthreads();
    if (t < 256 && j < 8) {
        float s = b3[j];
#pragma unroll
        for (int k = 0; k < 16; ++k) s = fmaf(h2s[p][k], W3[k * 8 + j], s);
        h3s[p][j] = fmaxf(s, 0.f);
    }
    __syncthreads();
    if (t < 256 && j == 0) {
        float z = b4[0];
#pragma unroll
        for (int k = 0; k < 8; ++k) z = fmaf(h3s[p][k], W4[k], z);
        a_s[p] = (p < PXB) ? (1.f / (1.f + expf(-z))) : 0.f;
    }
    __syncthreads();

    // ---- phase 4: a.x partials from f32 LDS; thread t owns 4 channels ----
    f32x4 s = {0.f, 0.f, 0.f, 0.f};
#pragma unroll
    for (int pp = 0; pp < PXB; ++pp) {
        const f32x4 v = *(const f32x4*)((const char*)xs + pp * 8192
                                        + ((t * 16) ^ (pp << 4)));
        const float ap = a_s[pp];
        s[0] = fmaf(ap, v[0], s[0]); s[1] = fmaf(ap, v[1], s[1]);
        s[2] = fmaf(ap, v[2], s[2]); s[3] = fmaf(ap, v[3], s[3]);
    }
    *(f32x4*)(part2 + (size_t)blk * CIN + t * 4) = s;
    if (t == 0) {
        float sa = 0.f;
#pragma unroll
        for (int pp = 0; pp < PXB; ++pp) sa += a_s[pp];
        asum_part[blk] = sa;
    }
}

// ---- kernel 2: finalize. grid 64 (one per image), block 512. ----
__global__ __launch_bounds__(512) void gap_final(
    const float* __restrict__ asum_part, const float* __restrict__ part2,
    float* __restrict__ out)
{
    __shared__ float red[BPIMG];
    const int b = blockIdx.x, t = threadIdx.x;
    if (t < BPIMG) red[t] = asum_part[b * BPIMG + t];
    __syncthreads();
    float ssum = 0.f;
#pragma unroll
    for (int z = 0; z < BPIMG; ++z) ssum += red[z];
    const float inv = 1.f / ssum;

    const int c0 = t * 4;
    f32x4 acc = {0.f, 0.f, 0.f, 0.f};
#pragma unroll
    for (int z = 0; z < BPIMG; ++z) {
        const f32x4 pv = *(const f32x4*)(part2 + (size_t)(b * BPIMG + z) * CIN + c0);
        acc += pv;
    }
    f32x4 r = acc * inv;
    *(f32x4*)(out + (size_t)b * CIN + c0) = r;
}

extern "C" void kernel_launch(void* const* d_in, const int* in_sizes, int n_in,
                              void* d_out, int out_size, void* d_ws, size_t ws_size,
                              hipStream_t stream)
{
    const float* x  = (const float*)d_in[0];
    const float* W1 = (const float*)d_in[1];
    const float* b1 = (const float*)d_in[2];
    const float* W2 = (const float*)d_in[3];
    const float* b2 = (const float*)d_in[4];
    const float* W3 = (const float*)d_in[5];
    const float* b3 = (const float*)d_in[6];
    const float* W4 = (const float*)d_in[7];
    const float* b4 = (const float*)d_in[8];
    float* out = (float*)d_out;

    // ws layout: Wf bf16 [131072] @0 (256KB) | asum_part f32 [1792] @512KB |
    //            part2 f32 [1792][2048] @1MB (14.7MB). Total ~15.7 MB.
    unsigned short* Wf = (unsigned short*)d_ws;
    float* asum_part = (float*)((char*)d_ws + (512 << 10));
    float* part2     = (float*)((char*)d_ws + (1 << 20));

    conv_w1<<<512, 256, 0, stream>>>(W1, Wf);
    fused_attn_gap<<<NBLK, 512, 0, stream>>>(x, Wf, b1, W2, b2, W3, b3, W4, b4,
                                             part2, asum_part);
    gap_final<<<NB, 512, 0, stream>>>(asum_part, part2, out);
}

// Round 10
// 224.572 us; speedup vs baseline: 1.1059x; 1.1059x over previous
//
#include <hip/hip_runtime.h>
#include <math.h>

// ---- problem constants ----
#define CIN  2048
#define NB   64               // batch
#define PPIX 196              // pixels per image
#define PXB  7                // pixels per block (7 | 196: no image straddle)
#define BPIMG 28              // blocks per image
#define NBLK (NB * BPIMG)     // 1792 blocks

typedef float f32x4 __attribute__((ext_vector_type(4)));

__device__ inline unsigned short f2bf(float f) {
    unsigned int u = __float_as_uint(f);
    u = (u + 0x7fffu + ((u >> 16) & 1u)) >> 16;
    return (unsigned short)u;
}
__device__ inline float bf2f(unsigned short u) {
    return __uint_as_float((unsigned int)u << 16);
}

// ---- kernel 0: W1 f32 [2048][64] -> Wb bf16, SAME layout (no transpose).
// Lane n reads Wb[k*64+n]: 128B coalesced per wave per k. Halves L2 traffic.
__global__ __launch_bounds__(256) void wb_conv(
    const float* __restrict__ W1, unsigned short* __restrict__ Wb)
{
    const int id = blockIdx.x * 256 + threadIdx.x;   // 0..131071
    Wb[id] = f2bf(W1[id]);
}

// ---- kernel 1: FUSED pure-VALU attention + weighted-GAP partials ----
// Block = 7 pixels, 512 threads = 8 waves, 2 blocks/CU (LDS ~73KB).
// Stage: x rows f32 -> LDS via global_load_lds, linear+coalesced.
// h1 GEMV: lane = channel n, wave wv = K-slice [wv*256,+256). x read as
//   lane-uniform LDS broadcasts (conflict-free); Wb read coalesced 128B/k.
//   acc[7]: 7 independent FMA chains per lane. 8 K-partials reduced in LDS.
// Tail: 64->16->8->1 MLP, then sigmoid -> a_s[7].
// Phase 4: a.x from the SAME f32 LDS tile (x read once): thread t owns
//   exactly 4 channels (512*4 = 2048 -- in bounds), 7 FMAs, f32 precision.
__global__ __launch_bounds__(512, 4) void attn_gap(
    const float* __restrict__ x, const unsigned short* __restrict__ Wb,
    const float* __restrict__ b1,
    const float* __restrict__ W2, const float* __restrict__ b2,
    const float* __restrict__ W3, const float* __restrict__ b3,
    const float* __restrict__ W4, const float* __restrict__ b4,
    float* __restrict__ part2, float* __restrict__ asum_part)
{
    __shared__ float xs[PXB * CIN];      // 56 KB, linear f32
    __shared__ float h1p[8][PXB][64];    // 14 KB K-split partials
    __shared__ float h1s[PXB][68];       // +4 pad: conflict-free tail reads
    __shared__ float h2s[PXB][16];
    __shared__ float h3s[PXB][8];
    __shared__ float a_s[PXB];

    const int t    = threadIdx.x;        // 0..511
    const int wv   = t >> 6;             // wave 0..7 -> K-slice
    const int lane = t & 63;             // = output channel n
    const int blk  = blockIdx.x;
    const size_t pix0 = (size_t)blk * PXB;

    // ---- stage: wave wv DMAs its 1KB segment of each of the 7 rows ----
#pragma unroll
    for (int r = 0; r < PXB; ++r)
        __builtin_amdgcn_global_load_lds(
            x + (pix0 + r) * (size_t)CIN + wv * 256 + lane * 4,
            &xs[r * CIN + wv * 256], 16, 0, 0);
    __syncthreads();   // implies vmcnt(0): tile resident

    // ---- h1 GEMV over this wave's K-slice ----
    const unsigned short* wp = Wb + (size_t)(wv * 256) * 64 + lane;
    float a0 = 0.f, a1 = 0.f, a2 = 0.f, a3 = 0.f, a4 = 0.f, a5 = 0.f, a6 = 0.f;
#pragma unroll 2
    for (int kb = 0; kb < 64; ++kb) {    // 4 k per batch
        const int k0 = kb * 4;
        const float w0 = bf2f(wp[(k0 + 0) * 64]);
        const float w1 = bf2f(wp[(k0 + 1) * 64]);
        const float w2 = bf2f(wp[(k0 + 2) * 64]);
        const float w3 = bf2f(wp[(k0 + 3) * 64]);
        const int xo = wv * 256 + k0;    // uniform -> LDS broadcast reads
        const f32x4 q0 = *(const f32x4*)&xs[0 * CIN + xo];
        const f32x4 q1 = *(const f32x4*)&xs[1 * CIN + xo];
        const f32x4 q2 = *(const f32x4*)&xs[2 * CIN + xo];
        const f32x4 q3 = *(const f32x4*)&xs[3 * CIN + xo];
        const f32x4 q4 = *(const f32x4*)&xs[4 * CIN + xo];
        const f32x4 q5 = *(const f32x4*)&xs[5 * CIN + xo];
        const f32x4 q6 = *(const f32x4*)&xs[6 * CIN + xo];
        a0 = fmaf(q0[3], w3, fmaf(q0[2], w2, fmaf(q0[1], w1, fmaf(q0[0], w0, a0))));
        a1 = fmaf(q1[3], w3, fmaf(q1[2], w2, fmaf(q1[1], w1, fmaf(q1[0], w0, a1))));
        a2 = fmaf(q2[3], w3, fmaf(q2[2], w2, fmaf(q2[1], w1, fmaf(q2[0], w0, a2))));
        a3 = fmaf(q3[3], w3, fmaf(q3[2], w2, fmaf(q3[1], w1, fmaf(q3[0], w0, a3))));
        a4 = fmaf(q4[3], w3, fmaf(q4[2], w2, fmaf(q4[1], w1, fmaf(q4[0], w0, a4))));
        a5 = fmaf(q5[3], w3, fmaf(q5[2], w2, fmaf(q5[1], w1, fmaf(q5[0], w0, a5))));
        a6 = fmaf(q6[3], w3, fmaf(q6[2], w2, fmaf(q6[1], w1, fmaf(q6[0], w0, a6))));
    }
    h1p[wv][0][lane] = a0; h1p[wv][1][lane] = a1; h1p[wv][2][lane] = a2;
    h1p[wv][3][lane] = a3; h1p[wv][4][lane] = a4; h1p[wv][5][lane] = a5;
    h1p[wv][6][lane] = a6;
    __syncthreads();

    // ---- reduce 8 K-partials -> h1 (+bias, relu). 448 threads. ----
    if (t < 448) {
        const int p = t >> 6, n = t & 63;
        float s = b1[n];
#pragma unroll
        for (int w = 0; w < 8; ++w) s += h1p[w][p][n];
        h1s[p][n] = fmaxf(s, 0.f);
    }
    __syncthreads();

    // ---- MLP tail ----
    if (t < 112) {                       // 7 px * 16 j
        const int p = t >> 4, j = t & 15;
        float s = b2[j];
#pragma unroll
        for (int k = 0; k < 64; ++k) s = fmaf(h1s[p][k], W2[k * 16 + j], s);
        h2s[p][j] = fmaxf(s, 0.f);
    }
    __syncthreads();
    if (t < 56) {                        // 7 px * 8 j
        const int p = t >> 3, j = t & 7;
        float s = b3[j];
#pragma unroll
        for (int k = 0; k < 16; ++k) s = fmaf(h2s[p][k], W3[k * 8 + j], s);
        h3s[p][j] = fmaxf(s, 0.f);
    }
    __syncthreads();
    if (t < PXB) {
        float z = b4[0];
#pragma unroll
        for (int k = 0; k < 8; ++k) z = fmaf(h3s[t][k], W4[k], z);
        a_s[t] = 1.f / (1.f + expf(-z));
    }
    __syncthreads();

    // ---- phase 4: a.x partials; thread t owns 4 channels (t*4 < 2048) ----
    {
        const int c0 = t * 4;
        f32x4 s = {0.f, 0.f, 0.f, 0.f};
#pragma unroll
        for (int p = 0; p < PXB; ++p) {
            const float ap = a_s[p];
            const f32x4 v = *(const f32x4*)&xs[p * CIN + c0];
            s[0] = fmaf(ap, v[0], s[0]); s[1] = fmaf(ap, v[1], s[1]);
            s[2] = fmaf(ap, v[2], s[2]); s[3] = fmaf(ap, v[3], s[3]);
        }
        *(f32x4*)(part2 + (size_t)blk * CIN + c0) = s;
    }
    if (t == 0) {
        float sa = 0.f;
#pragma unroll
        for (int p = 0; p < PXB; ++p) sa += a_s[p];
        asum_part[blk] = sa;
    }
}

// ---- kernel 2: finalize. grid 64 (one per image), block 512. ----
__global__ __launch_bounds__(512) void gap_final(
    const float* __restrict__ asum_part, const float* __restrict__ part2,
    float* __restrict__ out)
{
    __shared__ float red[BPIMG];
    const int b = blockIdx.x, t = threadIdx.x;
    if (t < BPIMG) red[t] = asum_part[b * BPIMG + t];
    __syncthreads();
    float ssum = 0.f;
#pragma unroll
    for (int z = 0; z < BPIMG; ++z) ssum += red[z];
    const float inv = 1.f / ssum;

    const int c0 = t * 4;
    f32x4 acc = {0.f, 0.f, 0.f, 0.f};
#pragma unroll
    for (int z = 0; z < BPIMG; ++z) {
        const f32x4 pv = *(const f32x4*)(part2 + (size_t)(b * BPIMG + z) * CIN + c0);
        acc += pv;
    }
    f32x4 r = acc * inv;
    *(f32x4*)(out + (size_t)b * CIN + c0) = r;
}

extern "C" void kernel_launch(void* const* d_in, const int* in_sizes, int n_in,
                              void* d_out, int out_size, void* d_ws, size_t ws_size,
                              hipStream_t stream)
{
    const float* x  = (const float*)d_in[0];
    const float* W1 = (const float*)d_in[1];
    const float* b1 = (const float*)d_in[2];
    const float* W2 = (const float*)d_in[3];
    const float* b2 = (const float*)d_in[4];
    const float* W3 = (const float*)d_in[5];
    const float* b3 = (const float*)d_in[6];
    const float* W4 = (const float*)d_in[7];
    const float* b4 = (const float*)d_in[8];
    float* out = (float*)d_out;

    // ws layout: Wb bf16 [131072] @0 (256KB) | asum_part f32 [1792] @512KB |
    //            part2 f32 [1792][2048] @1MB (14.7MB). Total ~15.7 MB.
    unsigned short* Wb = (unsigned short*)d_ws;
    float* asum_part = (float*)((char*)d_ws + (512 << 10));
    float* part2     = (float*)((char*)d_ws + (1 << 20));

    wb_conv<<<512, 256, 0, stream>>>(W1, Wb);
    attn_gap<<<NBLK, 512, 0, stream>>>(x, Wb, b1, W2, b2, W3, b3, W4, b4,
                                       part2, asum_part);
    gap_final<<<NB, 512, 0, stream>>>(asum_part, part2, out);
}